// Round 9
// baseline (316.314 us; speedup 1.0000x reference)
//
#include <hip/hip_runtime.h>
#include <hip/hip_bf16.h>

typedef __hip_bfloat16 bf16;
typedef short bf16x8 __attribute__((ext_vector_type(8)));
typedef float f32x4 __attribute__((ext_vector_type(4)));
typedef unsigned int u32;

static __device__ __forceinline__ float bfu2f(unsigned short u) { return __uint_as_float((u32)u << 16); }
static __device__ __forceinline__ u32 pack2(float a, float b) {
    return (u32)__bfloat16_as_ushort(__float2bfloat16(a))
         | ((u32)__bfloat16_as_ushort(__float2bfloat16(b)) << 16);
}
static __device__ __forceinline__ float wave_sum(float v) {
    #pragma unroll
    for (int off = 32; off > 0; off >>= 1) v += __shfl_xor(v, off);
    return v;
}

// ---------------------------------------------------------------------------
// Fused fp32->bf16 cast of Q, K, Wq, Wk, Wv, Wo. 4096 elems/block, 16/thread.
// ---------------------------------------------------------------------------
__global__ __launch_bounds__(256) void castall(const float* __restrict__ Q,  const float* __restrict__ K,
                                               const float* __restrict__ Wq, const float* __restrict__ Wk,
                                               const float* __restrict__ Wv, const float* __restrict__ Wo,
                                               bf16* __restrict__ dQ,  bf16* __restrict__ dK,
                                               bf16* __restrict__ dWq, bf16* __restrict__ dWk,
                                               bf16* __restrict__ dWv, bf16* __restrict__ dWo)
{
    const int b = blockIdx.x;
    const float* src; bf16* dst; size_t off;
    if (b < 1024)      { src = Q;  dst = dQ;  off = (size_t)b * 4096; }
    else if (b < 2048) { src = K;  dst = dK;  off = (size_t)(b - 1024) * 4096; }
    else {
        const int wb = b - 2048, wi = wb >> 6;
        off = (size_t)(wb & 63) * 4096;
        src = wi == 0 ? Wq : wi == 1 ? Wk : wi == 2 ? Wv : Wo;
        dst = wi == 0 ? dWq : wi == 1 ? dWk : wi == 2 ? dWv : dWo;
    }
    const size_t p = off + threadIdx.x * 16;
    const float4 v0 = *(const float4*)(src + p);
    const float4 v1 = *(const float4*)(src + p + 4);
    const float4 v2 = *(const float4*)(src + p + 8);
    const float4 v3 = *(const float4*)(src + p + 12);
    uint4 o0, o1;
    o0.x = pack2(v0.x, v0.y); o0.y = pack2(v0.z, v0.w);
    o0.z = pack2(v1.x, v1.y); o0.w = pack2(v1.z, v1.w);
    o1.x = pack2(v2.x, v2.y); o1.y = pack2(v2.z, v2.w);
    o1.z = pack2(v3.x, v3.y); o1.w = pack2(v3.z, v3.w);
    *(uint4*)(dst + p)     = o0;
    *(uint4*)(dst + p + 8) = o1;
}

// ---------------------------------------------------------------------------
// Fused QKV projection GEMM (NT) — DIRECT-FRAGMENT, no LDS, no barriers.
// K is contiguous (NT layout), so each lane's MFMA fragment is one
// global dwordx4: A[m=wm+16i+fr][k0 + fq*8 ..+8]. Compiler interleaves
// buffer loads with MFMAs using fine-grained vmcnt (AITER-style K-loop).
// Block = 4 waves 2x2, each 64x64 -> 128x128 tile. Grid (64, 12).
// ---------------------------------------------------------------------------
__global__ __launch_bounds__(256) void gemm_qkv(const bf16* __restrict__ Aq, const bf16* __restrict__ Ak,
                                                const bf16* __restrict__ Wq, const bf16* __restrict__ Wk,
                                                const bf16* __restrict__ Wv,
                                                const float* __restrict__ bq, const float* __restrict__ bk,
                                                const float* __restrict__ bv,
                                                bf16* __restrict__ oQ, bf16* __restrict__ oK,
                                                bf16* __restrict__ oV)
{
    const int tid = threadIdx.x, lane = tid & 63, wave = tid >> 6;
    const int yy = blockIdx.y, wi = yy >> 2;
    const bf16* A     = wi == 0 ? Aq : Ak;
    const bf16* W     = wi == 0 ? Wq : wi == 1 ? Wk : Wv;
    const float* bias = wi == 0 ? bq : wi == 1 ? bk : bv;
    bf16* out         = wi == 0 ? oQ : wi == 1 ? oK : oV;
    const int mode    = wi == 2 ? 2 : 1;
    const int bm = blockIdx.x * 128;
    const int bn = (yy & 3) * 128;

    const int wm = (wave >> 1) * 64, wn = (wave & 1) * 64;
    const int fr = lane & 15, fq = lane >> 4;

    f32x4 acc[4][4] = {};
    const bf16* Ap = A + (size_t)(bm + wm + fr) * 512 + fq * 8;
    const bf16* Wp = W + (size_t)(bn + wn + fr) * 512 + fq * 8;

    #pragma unroll 2
    for (int k0 = 0; k0 < 512; k0 += 32) {
        bf16x8 fa[4], fb[4];
        #pragma unroll
        for (int i = 0; i < 4; i++) {
            fa[i] = *(const bf16x8*)(Ap + (size_t)(16 * i) * 512 + k0);
            fb[i] = *(const bf16x8*)(Wp + (size_t)(16 * i) * 512 + k0);
        }
        #pragma unroll
        for (int i = 0; i < 4; i++)
            #pragma unroll
            for (int j = 0; j < 4; j++)
                acc[i][j] = __builtin_amdgcn_mfma_f32_16x16x32_bf16(fa[i], fb[j], acc[i][j], 0, 0, 0);
    }

    const int r0 = fq * 4;
    #pragma unroll
    for (int i = 0; i < 4; i++) {
        #pragma unroll
        for (int j = 0; j < 4; j++) {
            const int col = bn + wn + 16 * j + fr;
            const float bv2 = bias[col];
            #pragma unroll
            for (int r = 0; r < 4; r++) {
                const int row = bm + wm + 16 * i + r0 + r;
                const float v = acc[i][j][r] + bv2;
                const int b = row >> 10, n = row & 1023;
                const int h = col >> 6,  d = col & 63;
                size_t idx;
                if (mode == 1) idx = ((size_t)(b * 8 + h) * 1024 + n) * 64 + d;
                else           idx = ((size_t)(b * 8 + h) * 64 + d) * 1024 + n;
                out[idx] = __float2bfloat16(v);
            }
        }
    }
}

// ---------------------------------------------------------------------------
// O-projection GEMM (NT) — direct-fragment, no LDS/barriers.
// 64x128 tile, 4 waves split N (wave tile 64x32, acc 4x2). Grid (128, 4).
// ---------------------------------------------------------------------------
__global__ __launch_bounds__(256) void gemm_o(const bf16* __restrict__ A,
                                              const bf16* __restrict__ W,
                                              const float* __restrict__ bias,
                                              bf16* __restrict__ out)
{
    const int tid = threadIdx.x, lane = tid & 63, wave = tid >> 6;
    const int bm = blockIdx.x * 64;
    const int bn = blockIdx.y * 128;
    const int wn = wave * 32;
    const int fr = lane & 15, fq = lane >> 4;

    f32x4 acc[4][2] = {};
    const bf16* Ap = A + (size_t)(bm + fr) * 512 + fq * 8;
    const bf16* Wp = W + (size_t)(bn + wn + fr) * 512 + fq * 8;

    #pragma unroll 2
    for (int k0 = 0; k0 < 512; k0 += 32) {
        bf16x8 fa[4], fb[2];
        #pragma unroll
        for (int i = 0; i < 4; i++)
            fa[i] = *(const bf16x8*)(Ap + (size_t)(16 * i) * 512 + k0);
        #pragma unroll
        for (int j = 0; j < 2; j++)
            fb[j] = *(const bf16x8*)(Wp + (size_t)(16 * j) * 512 + k0);
        #pragma unroll
        for (int i = 0; i < 4; i++)
            #pragma unroll
            for (int j = 0; j < 2; j++)
                acc[i][j] = __builtin_amdgcn_mfma_f32_16x16x32_bf16(fa[i], fb[j], acc[i][j], 0, 0, 0);
    }

    const int r0 = fq * 4;
    #pragma unroll
    for (int i = 0; i < 4; i++) {
        #pragma unroll
        for (int j = 0; j < 2; j++) {
            const int col = bn + wn + 16 * j + fr;
            const float bv = bias[col];
            #pragma unroll
            for (int r = 0; r < 4; r++) {
                const int row = bm + 16 * i + r0 + r;
                out[(size_t)row * 512 + col] = __float2bfloat16(acc[i][j][r] + bv);
            }
        }
    }
}

// ---------------------------------------------------------------------------
// MFMA flash attention — S^T form, fixed-max softmax, DIRECT-FRAGMENT K/V
// loads from global (no staging LDS, ZERO __syncthreads). Only P^T goes
// through per-wave LDS (ds_write/ds_read, lgkmcnt only). 4 waves/block share
// K/V chunk reads -> L1 hits. XCD swizzle: all 16 blocks of a bh land on one
// XCD (id%8) so K/V is fetched from HBM once per XCD.
// Qh [b,h,n,64], Kh [b,h,m,64], VhT [b,h,d,m]. Flat grid 1024, 4 waves,
// wave = 16 q-rows.
// ---------------------------------------------------------------------------
__global__ __launch_bounds__(256) void attn_mfma(const bf16* __restrict__ Qh,
                                                 const bf16* __restrict__ Kh,
                                                 const bf16* __restrict__ VhT,
                                                 bf16* __restrict__ Oc)
{
    __shared__ bf16 Ps[4][16 * 72];      // per-wave P^T rows n, pad 8

    const int tid = threadIdx.x, lane = tid & 63, w = tid >> 6;
    const int id = blockIdx.x;
    const int bh = (id & 7) * 8 + (id >> 7);        // XCD-local bh grouping
    const int wq = ((id >> 3) & 15) * 64 + w * 16;  // q-row base

    const bf16* Qb = Qh  + ((size_t)bh * 1024 + wq) * 64;
    const bf16* Kb = Kh  + (size_t)bh * 1024 * 64;
    const bf16* Vb = VhT + (size_t)bh * 64 * 1024;

    const int fl = lane & 15, fq = lane >> 4;

    bf16x8 qf0 = *(const bf16x8*)(Qb + fl * 64 + fq * 8);
    bf16x8 qf1 = *(const bf16x8*)(Qb + fl * 64 + 32 + fq * 8);

    f32x4 o[4] = {};
    float lsum = 0.f;
    const float sc2 = 0.04419417382415922f * 1.4426950408889634f; // /sqrt(512)*log2e

    // per-lane fragment row bases
    const bf16* KpA = Kb + (size_t)fl * 64 + fq * 8;        // + (m0+16tm)*64 ; +32 for hi
    const bf16* VpA = Vb + (size_t)fl * 1024 + fq * 8;      // + jd*16*1024 + m0 ; +32

    for (int kt = 0; kt < 16; kt++) {
        const int m0 = kt * 64;

        // K fragments (A-operand of S^T = K Q^T), direct from global
        bf16x8 kf[4][2];
        #pragma unroll
        for (int tm = 0; tm < 4; tm++) {
            const bf16* p = KpA + (size_t)(m0 + 16 * tm) * 64;
            kf[tm][0] = *(const bf16x8*)(p);
            kf[tm][1] = *(const bf16x8*)(p + 32);
        }
        f32x4 st[4] = {};
        #pragma unroll
        for (int tm = 0; tm < 4; tm++) {
            st[tm] = __builtin_amdgcn_mfma_f32_16x16x32_bf16(kf[tm][0], qf0, st[tm], 0, 0, 0);
            st[tm] = __builtin_amdgcn_mfma_f32_16x16x32_bf16(kf[tm][1], qf1, st[tm], 0, 0, 0);
        }

        // V^T fragments (A-operand of O^T += V^T P^T) — issue early to overlap
        bf16x8 vf[4][2];
        #pragma unroll
        for (int jd = 0; jd < 4; jd++) {
            const bf16* p = VpA + (size_t)(16 * jd) * 1024 + m0;
            vf[jd][0] = *(const bf16x8*)(p);
            vf[jd][1] = *(const bf16x8*)(p + 32);
        }

        // p = exp2(s*sc2); per-lane l; pack P^T to per-wave LDS (no barrier)
        #pragma unroll
        for (int tm = 0; tm < 4; tm++) {
            float p0 = __builtin_amdgcn_exp2f(st[tm][0] * sc2);
            float p1 = __builtin_amdgcn_exp2f(st[tm][1] * sc2);
            float p2 = __builtin_amdgcn_exp2f(st[tm][2] * sc2);
            float p3 = __builtin_amdgcn_exp2f(st[tm][3] * sc2);
            lsum += (p0 + p1) + (p2 + p3);
            uint2 pk;
            pk.x = pack2(p0, p1);
            pk.y = pack2(p2, p3);
            *(uint2*)(&Ps[w][fl * 72 + 16 * tm + fq * 4]) = pk;
        }

        bf16x8 pf0 = *(const bf16x8*)(&Ps[w][fl * 72 + fq * 8]);
        bf16x8 pf1 = *(const bf16x8*)(&Ps[w][fl * 72 + 32 + fq * 8]);
        #pragma unroll
        for (int jd = 0; jd < 4; jd++) {
            o[jd] = __builtin_amdgcn_mfma_f32_16x16x32_bf16(vf[jd][0], pf0, o[jd], 0, 0, 0);
            o[jd] = __builtin_amdgcn_mfma_f32_16x16x32_bf16(vf[jd][1], pf1, o[jd], 0, 0, 0);
        }
    }

    lsum += __shfl_xor(lsum, 16);
    lsum += __shfl_xor(lsum, 32);
    const float linv = 1.f / lsum;

    const int b = bh >> 3, h = bh & 7;
    const size_t obase = ((size_t)(b * 1024 + wq + fl)) * 512 + h * 64;
    #pragma unroll
    for (int jd = 0; jd < 4; jd++) {
        const ushort4 qr = *(const ushort4*)(Qb + fl * 64 + 16 * jd + fq * 4);
        const float v0 = o[jd][0] * linv + bfu2f(qr.x);
        const float v1 = o[jd][1] * linv + bfu2f(qr.y);
        const float v2 = o[jd][2] * linv + bfu2f(qr.z);
        const float v3 = o[jd][3] * linv + bfu2f(qr.w);
        uint2 w2;
        w2.x = pack2(v0, v1);
        w2.y = pack2(v2, v3);
        *(uint2*)(&Oc[obase + 16 * jd + fq * 4]) = w2;
    }
}

// ---------------------------------------------------------------------------
// LayerNorm over rows of 512 — wave/row, 8 consecutive elems/lane.
// ---------------------------------------------------------------------------
__global__ __launch_bounds__(256) void ln0(const bf16* __restrict__ X,
                                           const float* __restrict__ g,
                                           const float* __restrict__ be,
                                           bf16* __restrict__ Y)
{
    const int lane = threadIdx.x & 63;
    const int row = blockIdx.x * 4 + (threadIdx.x >> 6);
    const size_t base = (size_t)row * 512 + lane * 8;
    const bf16x8 xv = *(const bf16x8*)(X + base);
    float x[8];
    #pragma unroll
    for (int j = 0; j < 8; j++) x[j] = bfu2f((unsigned short)xv[j]);
    float s = 0.f, s2 = 0.f;
    #pragma unroll
    for (int j = 0; j < 8; j++) { s += x[j]; s2 += x[j] * x[j]; }
    s = wave_sum(s); s2 = wave_sum(s2);
    const float mean = s * (1.f / 512.f);
    const float var = s2 * (1.f / 512.f) - mean * mean;
    const float rs = rsqrtf(fmaxf(var, 0.f) + 1e-5f);
    const float4 gv0 = *(const float4*)(g + lane * 8);
    const float4 gv1 = *(const float4*)(g + lane * 8 + 4);
    const float4 bv0 = *(const float4*)(be + lane * 8);
    const float4 bv1 = *(const float4*)(be + lane * 8 + 4);
    uint4 ov;
    ov.x = pack2((x[0]-mean)*rs*gv0.x + bv0.x, (x[1]-mean)*rs*gv0.y + bv0.y);
    ov.y = pack2((x[2]-mean)*rs*gv0.z + bv0.z, (x[3]-mean)*rs*gv0.w + bv0.w);
    ov.z = pack2((x[4]-mean)*rs*gv1.x + bv1.x, (x[5]-mean)*rs*gv1.y + bv1.y);
    ov.w = pack2((x[6]-mean)*rs*gv1.z + bv1.z, (x[7]-mean)*rs*gv1.w + bv1.w);
    *(uint4*)(Y + base) = ov;
}

__global__ __launch_bounds__(256) void ln1(const bf16* __restrict__ X,
                                           const bf16* __restrict__ R,
                                           const float* __restrict__ g,
                                           const float* __restrict__ be,
                                           float* __restrict__ Y)
{
    const int lane = threadIdx.x & 63;
    const int row = blockIdx.x * 4 + (threadIdx.x >> 6);
    const size_t base = (size_t)row * 512 + lane * 8;
    const bf16x8 xv = *(const bf16x8*)(X + base);
    const bf16x8 rv = *(const bf16x8*)(R + base);
    float x[8];
    #pragma unroll
    for (int j = 0; j < 8; j++)
        x[j] = bfu2f((unsigned short)rv[j]) + fmaxf(bfu2f((unsigned short)xv[j]), 0.f);
    float s = 0.f, s2 = 0.f;
    #pragma unroll
    for (int j = 0; j < 8; j++) { s += x[j]; s2 += x[j] * x[j]; }
    s = wave_sum(s); s2 = wave_sum(s2);
    const float mean = s * (1.f / 512.f);
    const float var = s2 * (1.f / 512.f) - mean * mean;
    const float rs = rsqrtf(fmaxf(var, 0.f) + 1e-5f);
    const float4 gv0 = *(const float4*)(g + lane * 8);
    const float4 gv1 = *(const float4*)(g + lane * 8 + 4);
    const float4 bv0 = *(const float4*)(be + lane * 8);
    const float4 bv1 = *(const float4*)(be + lane * 8 + 4);
    float4 y0, y1;
    y0.x = (x[0]-mean)*rs*gv0.x + bv0.x; y0.y = (x[1]-mean)*rs*gv0.y + bv0.y;
    y0.z = (x[2]-mean)*rs*gv0.z + bv0.z; y0.w = (x[3]-mean)*rs*gv0.w + bv0.w;
    y1.x = (x[4]-mean)*rs*gv1.x + bv1.x; y1.y = (x[5]-mean)*rs*gv1.y + bv1.y;
    y1.z = (x[6]-mean)*rs*gv1.z + bv1.z; y1.w = (x[7]-mean)*rs*gv1.w + bv1.w;
    *(float4*)(Y + base)     = y0;
    *(float4*)(Y + base + 4) = y1;
}

// ---------------------------------------------------------------------------
extern "C" void kernel_launch(void* const* d_in, const int* in_sizes, int n_in,
                              void* d_out, int out_size, void* d_ws, size_t ws_size,
                              hipStream_t stream)
{
    const float* Q   = (const float*)d_in[0];
    const float* K   = (const float*)d_in[1];
    const float* Wq  = (const float*)d_in[2];
    const float* bq  = (const float*)d_in[3];
    const float* Wk  = (const float*)d_in[4];
    const float* bk  = (const float*)d_in[5];
    const float* Wv  = (const float*)d_in[6];
    const float* bv  = (const float*)d_in[7];
    const float* Wo  = (const float*)d_in[8];
    const float* bo  = (const float*)d_in[9];
    const float* g0  = (const float*)d_in[10];
    const float* be0 = (const float*)d_in[11];
    const float* g1  = (const float*)d_in[12];
    const float* be1 = (const float*)d_in[13];
    float* out = (float*)d_out;

    const size_t NQK = (size_t)8 * 1024 * 512;  // 4M
    const size_t NW  = (size_t)512 * 512;       // 256K
    bf16* ws   = (bf16*)d_ws;
    bf16* cQ   = ws;
    bf16* cK   = cQ + NQK;
    bf16* cWq  = cK + NQK;
    bf16* cWk  = cWq + NW;
    bf16* cWv  = cWk + NW;
    bf16* cWo  = cWv + NW;
    bf16* pQh  = cWo + NW;           // [b,h,n,d]
    bf16* pKh  = pQh + NQK;          // [b,h,m,d]
    bf16* pVhT = pKh + NQK;          // [b,h,d,m]
    bf16* pOc  = (bf16*)d_out;       // attn output staged in d_out
    bf16* pO1  = pKh;                // Kh dead after attn
    bf16* pTmp = pQh;                // Qh dead after attn

    castall<<<2304, 256, 0, stream>>>(Q, K, Wq, Wk, Wv, Wo, cQ, cK, cWq, cWk, cWv, cWo);
    gemm_qkv<<<dim3(64, 12), 256, 0, stream>>>(cQ, cK, cWq, cWk, cWv, bq, bk, bv, pQh, pKh, pVhT);
    attn_mfma<<<1024, 256, 0, stream>>>(pQh, pKh, pVhT, pOc);
    ln0<<<2048, 256, 0, stream>>>(pOc, g0, be0, pO1);
    gemm_o<<<dim3(128, 4), 256, 0, stream>>>(pO1, cWo, bo, pTmp);
    ln1<<<2048, 256, 0, stream>>>(pTmp, pO1, g1, be1, out);
}

// Round 10
// 187.396 us; speedup vs baseline: 1.6879x; 1.6879x over previous
//
#include <hip/hip_runtime.h>
#include <hip/hip_bf16.h>

typedef __hip_bfloat16 bf16;
typedef short bf16x8 __attribute__((ext_vector_type(8)));
typedef float f32x4 __attribute__((ext_vector_type(4)));
typedef unsigned int u32;

static __device__ __forceinline__ float bfu2f(unsigned short u) { return __uint_as_float((u32)u << 16); }
static __device__ __forceinline__ u32 pack2(float a, float b) {
    return (u32)__bfloat16_as_ushort(__float2bfloat16(a))
         | ((u32)__bfloat16_as_ushort(__float2bfloat16(b)) << 16);
}
static __device__ __forceinline__ float wave_sum(float v) {
    #pragma unroll
    for (int off = 32; off > 0; off >>= 1) v += __shfl_xor(v, off);
    return v;
}

// async global->LDS 16B copy (wave-uniform LDS base + lane*16 by HW).
static __device__ __forceinline__ void gll16(const bf16* g, bf16* l) {
    __builtin_amdgcn_global_load_lds((const __attribute__((address_space(1))) void*)g,
                                     (__attribute__((address_space(3))) void*)l,
                                     16, 0, 0);
}

// ---------------------------------------------------------------------------
// Fused fp32->bf16 cast of Q, K, Wq, Wk, Wv, Wo. 4096 elems/block, 16/thread.
// ---------------------------------------------------------------------------
__global__ __launch_bounds__(256) void castall(const float* __restrict__ Q,  const float* __restrict__ K,
                                               const float* __restrict__ Wq, const float* __restrict__ Wk,
                                               const float* __restrict__ Wv, const float* __restrict__ Wo,
                                               bf16* __restrict__ dQ,  bf16* __restrict__ dK,
                                               bf16* __restrict__ dWq, bf16* __restrict__ dWk,
                                               bf16* __restrict__ dWv, bf16* __restrict__ dWo)
{
    const int b = blockIdx.x;
    const float* src; bf16* dst; size_t off;
    if (b < 1024)      { src = Q;  dst = dQ;  off = (size_t)b * 4096; }
    else if (b < 2048) { src = K;  dst = dK;  off = (size_t)(b - 1024) * 4096; }
    else {
        const int wb = b - 2048, wi = wb >> 6;
        off = (size_t)(wb & 63) * 4096;
        src = wi == 0 ? Wq : wi == 1 ? Wk : wi == 2 ? Wv : Wo;
        dst = wi == 0 ? dWq : wi == 1 ? dWk : wi == 2 ? dWv : dWo;
    }
    const size_t p = off + threadIdx.x * 16;
    const float4 v0 = *(const float4*)(src + p);
    const float4 v1 = *(const float4*)(src + p + 4);
    const float4 v2 = *(const float4*)(src + p + 8);
    const float4 v3 = *(const float4*)(src + p + 12);
    uint4 o0, o1;
    o0.x = pack2(v0.x, v0.y); o0.y = pack2(v0.z, v0.w);
    o0.z = pack2(v1.x, v1.y); o0.w = pack2(v1.z, v1.w);
    o1.x = pack2(v2.x, v2.y); o1.y = pack2(v2.z, v2.w);
    o1.z = pack2(v3.x, v3.y); o1.w = pack2(v3.z, v3.w);
    *(uint4*)(dst + p)     = o0;
    *(uint4*)(dst + p + 8) = o1;
}

// ---------------------------------------------------------------------------
// Fused QKV projection GEMM (NT), 128x128 tiles, BK=64 single-buffered
// gll16 staging (8 iters, 2 barriers each), unpadded [128][64] LDS with
// granule swizzle LDS[row][g] = glob[row][g ^ (row&7)].
// Q/K-proj compute C^T (operand-swapped) so a lane's 4 acc regs are 4
// consecutive d -> uint2 stores; V-proj computes C normally (regs = 4
// consecutive n, contiguous in the [b,h,d,n] layout). Grid (64, 12).
// ---------------------------------------------------------------------------
__global__ __launch_bounds__(256) void gemm_qkv(const bf16* __restrict__ Aq, const bf16* __restrict__ Ak,
                                                const bf16* __restrict__ Wq, const bf16* __restrict__ Wk,
                                                const bf16* __restrict__ Wv,
                                                const float* __restrict__ bq, const float* __restrict__ bk,
                                                const float* __restrict__ bv,
                                                bf16* __restrict__ oQ, bf16* __restrict__ oK,
                                                bf16* __restrict__ oV)
{
    __shared__ bf16 Xs[128 * 64];
    __shared__ bf16 Ws[128 * 64];

    const int tid = threadIdx.x, lane = tid & 63, wave = tid >> 6;
    const int yy = blockIdx.y, wi = yy >> 2;
    const bf16* A     = wi == 0 ? Aq : Ak;
    const bf16* W     = wi == 0 ? Wq : wi == 1 ? Wk : Wv;
    const float* bias = wi == 0 ? bq : wi == 1 ? bk : bv;
    bf16* out         = wi == 0 ? oQ : wi == 1 ? oK : oV;
    const bool vmode  = (wi == 2);
    const int bm = blockIdx.x * 128;
    const int bn = (yy & 3) * 128;

    // staging: slot s = tid + 256c -> row (tid>>3)+32c, lds granule tid&7,
    // source granule (tid&7)^((tid>>3)&7)
    const int srow = tid >> 3;
    const int sg8  = (((tid & 7) ^ (srow & 7)) * 8);
    const int wm = (wave >> 1) * 64, wn = (wave & 1) * 64;
    const int fr = lane & 15, fq = lane >> 4;

    f32x4 acc[4][4] = {};
    const bf16* Ap = A + (size_t)(bm + srow) * 512 + sg8;
    const bf16* Wp = W + (size_t)(bn + srow) * 512 + sg8;
    const int ld = 8 * tid;

    for (int k0 = 0; k0 < 512; k0 += 64) {
        __syncthreads();
        #pragma unroll
        for (int c = 0; c < 4; c++) {
            gll16(Ap + k0 + (size_t)(32 * c) * 512, Xs + ld + 2048 * c);
            gll16(Wp + k0 + (size_t)(32 * c) * 512, Ws + ld + 2048 * c);
        }
        __syncthreads();

        #pragma unroll
        for (int c2 = 0; c2 < 2; c2++) {
            bf16x8 fx[4], fw[4];
            #pragma unroll
            for (int i = 0; i < 4; i++) {
                const int rx = wm + 16 * i + fr;
                const int rw = wn + 16 * i + fr;
                fx[i] = *(const bf16x8*)(&Xs[rx * 64 + (((c2 * 4 + fq) ^ (rx & 7)) * 8)]);
                fw[i] = *(const bf16x8*)(&Ws[rw * 64 + (((c2 * 4 + fq) ^ (rw & 7)) * 8)]);
            }
            if (vmode) {
                #pragma unroll
                for (int i = 0; i < 4; i++)
                    #pragma unroll
                    for (int j = 0; j < 4; j++)
                        acc[i][j] = __builtin_amdgcn_mfma_f32_16x16x32_bf16(fx[i], fw[j], acc[i][j], 0, 0, 0);
            } else {
                #pragma unroll
                for (int i = 0; i < 4; i++)
                    #pragma unroll
                    for (int j = 0; j < 4; j++)
                        acc[i][j] = __builtin_amdgcn_mfma_f32_16x16x32_bf16(fw[i], fx[j], acc[i][j], 0, 0, 0);
            }
        }
    }

    if (!vmode) {
        // C^T: acc[i][j] row = weight-col (d_full), col = data-row (n).
        // lane regs r -> 4 consecutive d. out[((b*8+h)*1024+n)*64+d]
        #pragma unroll
        for (int i = 0; i < 4; i++) {
            const int colb = bn + wn + 16 * i + 4 * fq;   // d_full base (mult of 4)
            const float4 b4 = *(const float4*)(bias + colb);
            const int h = colb >> 6, d0 = colb & 63;
            #pragma unroll
            for (int j = 0; j < 4; j++) {
                const int n = bm + wm + 16 * j + fr;
                const int b = n >> 10, nn = n & 1023;
                uint2 pk;
                pk.x = pack2(acc[i][j][0] + b4.x, acc[i][j][1] + b4.y);
                pk.y = pack2(acc[i][j][2] + b4.z, acc[i][j][3] + b4.w);
                *(uint2*)(out + ((size_t)(b * 8 + h) * 1024 + nn) * 64 + d0) = pk;
            }
        }
    } else {
        // C: acc[i][j] row = data-row (n), col = weight-col. regs = 4 consec n.
        // out[((b*8+h)*64+d)*1024+n]
        #pragma unroll
        for (int i = 0; i < 4; i++) {
            const int n0 = bm + wm + 16 * i + 4 * fq;     // mult of 4
            const int b = n0 >> 10, nn = n0 & 1023;
            #pragma unroll
            for (int j = 0; j < 4; j++) {
                const int col = bn + wn + 16 * j + fr;
                const float bv2 = bias[col];
                const int h = col >> 6, d = col & 63;
                uint2 pk;
                pk.x = pack2(acc[i][j][0] + bv2, acc[i][j][1] + bv2);
                pk.y = pack2(acc[i][j][2] + bv2, acc[i][j][3] + bv2);
                *(uint2*)(out + ((size_t)(b * 8 + h) * 64 + d) * 1024 + nn) = pk;
            }
        }
    }
}

// ---------------------------------------------------------------------------
// O-projection GEMM (NT), 64x128 tiles, BK=64 single-buffered gll16 staging.
// Operand-swapped (C^T) -> uint2 stores along columns. Grid (128, 4).
// Waves split the 128 weight cols (wave tile: 32 cols x 64 rows).
// ---------------------------------------------------------------------------
__global__ __launch_bounds__(256) void gemm_o(const bf16* __restrict__ A,
                                              const bf16* __restrict__ W,
                                              const float* __restrict__ bias,
                                              bf16* __restrict__ out)
{
    __shared__ bf16 Xs[64 * 64];
    __shared__ bf16 Ws[128 * 64];

    const int tid = threadIdx.x, lane = tid & 63, wave = tid >> 6;
    const int bm = blockIdx.x * 64;
    const int bn = blockIdx.y * 128;

    const int srow = tid >> 3;
    const int sg8  = (((tid & 7) ^ (srow & 7)) * 8);
    const int wn = wave * 32;
    const int fr = lane & 15, fq = lane >> 4;

    f32x4 acc[2][4] = {};
    const bf16* Ap = A + (size_t)(bm + srow) * 512 + sg8;
    const bf16* Wp = W + (size_t)(bn + srow) * 512 + sg8;
    const int ld = 8 * tid;

    for (int k0 = 0; k0 < 512; k0 += 64) {
        __syncthreads();
        #pragma unroll
        for (int c = 0; c < 2; c++)
            gll16(Ap + k0 + (size_t)(32 * c) * 512, Xs + ld + 2048 * c);
        #pragma unroll
        for (int c = 0; c < 4; c++)
            gll16(Wp + k0 + (size_t)(32 * c) * 512, Ws + ld + 2048 * c);
        __syncthreads();

        #pragma unroll
        for (int c2 = 0; c2 < 2; c2++) {
            bf16x8 fx[4], fw[2];
            #pragma unroll
            for (int j = 0; j < 4; j++) {
                const int rx = 16 * j + fr;
                fx[j] = *(const bf16x8*)(&Xs[rx * 64 + (((c2 * 4 + fq) ^ (rx & 7)) * 8)]);
            }
            #pragma unroll
            for (int i = 0; i < 2; i++) {
                const int rw = wn + 16 * i + fr;
                fw[i] = *(const bf16x8*)(&Ws[rw * 64 + (((c2 * 4 + fq) ^ (rw & 7)) * 8)]);
            }
            #pragma unroll
            for (int i = 0; i < 2; i++)
                #pragma unroll
                for (int j = 0; j < 4; j++)
                    acc[i][j] = __builtin_amdgcn_mfma_f32_16x16x32_bf16(fw[i], fx[j], acc[i][j], 0, 0, 0);
        }
    }

    #pragma unroll
    for (int i = 0; i < 2; i++) {
        const int colb = bn + wn + 16 * i + 4 * fq;
        const float4 b4 = *(const float4*)(bias + colb);
        #pragma unroll
        for (int j = 0; j < 4; j++) {
            const int row = bm + 16 * j + fr;
            uint2 pk;
            pk.x = pack2(acc[i][j][0] + b4.x, acc[i][j][1] + b4.y);
            pk.y = pack2(acc[i][j][2] + b4.z, acc[i][j][3] + b4.w);
            *(uint2*)(out + (size_t)row * 512 + colb) = pk;
        }
    }
}

// ---------------------------------------------------------------------------
// MFMA flash attention — S^T form, fixed-max softmax, single-buffered gll16
// K/V staging (round-7 structure), 32 q-rows per wave (2 q-tiles share each
// K/V fragment read). XCD swizzle: blocks of one bh land on one XCD.
// Qh [b,h,n,64], Kh [b,h,m,64], VhT [b,h,d,m]. Flat grid 512, 4 waves.
// ---------------------------------------------------------------------------
__global__ __launch_bounds__(256) void attn_mfma(const bf16* __restrict__ Qh,
                                                 const bf16* __restrict__ Kh,
                                                 const bf16* __restrict__ VhT,
                                                 bf16* __restrict__ Oc)
{
    __shared__ bf16 Ks[64 * 64];
    __shared__ bf16 Vs[64 * 64];
    __shared__ bf16 Ps[4][2][16 * 72];

    const int tid = threadIdx.x, lane = tid & 63, w = tid >> 6;
    const int id = blockIdx.x;
    const int bh = (id & 7) * 8 + (id >> 6);       // XCD-local bh grouping
    const int wq = ((id >> 3) & 7) * 128 + w * 32; // wave's first q-row

    const bf16* Qb = Qh  + ((size_t)bh * 1024 + wq) * 64;
    const bf16* Kb = Kh  + (size_t)bh * 1024 * 64;
    const bf16* Vb = VhT + (size_t)bh * 64 * 1024;

    const int fl = lane & 15, fq = lane >> 4;
    const int flk = fl & 7;
    const int gA = (fq ^ flk) * 8;
    const int gB = ((4 | fq) ^ flk) * 8;

    bf16x8 qf[2][2];
    #pragma unroll
    for (int t = 0; t < 2; t++) {
        qf[t][0] = *(const bf16x8*)(Qb + (16 * t + fl) * 64 + fq * 8);
        qf[t][1] = *(const bf16x8*)(Qb + (16 * t + fl) * 64 + 32 + fq * 8);
    }

    f32x4 o[2][4] = {};
    float lsum[2] = {0.f, 0.f};
    const float sc2 = 0.04419417382415922f * 1.4426950408889634f; // /sqrt(512)*log2e

    const int srow = tid >> 3;
    const int sg8  = (((tid & 7) ^ (srow & 7)) * 8);
    const bf16* KbR  = Kb + (size_t)srow * 64 + sg8;
    const bf16* VbR0 = Vb + (size_t)srow * 1024 + sg8;
    const bf16* VbR1 = Vb + (size_t)(srow + 32) * 1024 + sg8;
    const int ld = 8 * tid;

    for (int kt = 0; kt < 16; kt++) {
        const int m0 = kt * 64;
        __syncthreads();
        gll16(KbR + (size_t)m0 * 64,        Ks + ld);
        gll16(KbR + (size_t)(m0 + 32) * 64, Ks + 2048 + ld);
        gll16(VbR0 + m0,                    Vs + ld);
        gll16(VbR1 + m0,                    Vs + 2048 + ld);
        __syncthreads();

        // K fragments once, reused by both q-tiles
        bf16x8 kf[4][2];
        #pragma unroll
        for (int tm = 0; tm < 4; tm++) {
            kf[tm][0] = *(const bf16x8*)(&Ks[(16 * tm + fl) * 64 + gA]);
            kf[tm][1] = *(const bf16x8*)(&Ks[(16 * tm + fl) * 64 + gB]);
        }

        #pragma unroll
        for (int t = 0; t < 2; t++) {
            f32x4 st[4] = {};
            #pragma unroll
            for (int tm = 0; tm < 4; tm++) {
                st[tm] = __builtin_amdgcn_mfma_f32_16x16x32_bf16(kf[tm][0], qf[t][0], st[tm], 0, 0, 0);
                st[tm] = __builtin_amdgcn_mfma_f32_16x16x32_bf16(kf[tm][1], qf[t][1], st[tm], 0, 0, 0);
            }
            #pragma unroll
            for (int tm = 0; tm < 4; tm++) {
                float p0 = __builtin_amdgcn_exp2f(st[tm][0] * sc2);
                float p1 = __builtin_amdgcn_exp2f(st[tm][1] * sc2);
                float p2 = __builtin_amdgcn_exp2f(st[tm][2] * sc2);
                float p3 = __builtin_amdgcn_exp2f(st[tm][3] * sc2);
                lsum[t] += (p0 + p1) + (p2 + p3);
                uint2 pk;
                pk.x = pack2(p0, p1);
                pk.y = pack2(p2, p3);
                *(uint2*)(&Ps[w][t][fl * 72 + 16 * tm + fq * 4]) = pk;
            }
        }

        // V^T fragments once, reused by both q-tiles
        bf16x8 vf[4][2];
        #pragma unroll
        for (int jd = 0; jd < 4; jd++) {
            vf[jd][0] = *(const bf16x8*)(&Vs[(16 * jd + fl) * 64 + gA]);
            vf[jd][1] = *(const bf16x8*)(&Vs[(16 * jd + fl) * 64 + gB]);
        }
        #pragma unroll
        for (int t = 0; t < 2; t++) {
            bf16x8 pf0 = *(const bf16x8*)(&Ps[w][t][fl * 72 + fq * 8]);
            bf16x8 pf1 = *(const bf16x8*)(&Ps[w][t][fl * 72 + 32 + fq * 8]);
            #pragma unroll
            for (int jd = 0; jd < 4; jd++) {
                o[t][jd] = __builtin_amdgcn_mfma_f32_16x16x32_bf16(vf[jd][0], pf0, o[t][jd], 0, 0, 0);
                o[t][jd] = __builtin_amdgcn_mfma_f32_16x16x32_bf16(vf[jd][1], pf1, o[t][jd], 0, 0, 0);
            }
        }
    }

    const int b = bh >> 3, h = bh & 7;
    #pragma unroll
    for (int t = 0; t < 2; t++) {
        float ls = lsum[t];
        ls += __shfl_xor(ls, 16);
        ls += __shfl_xor(ls, 32);
        const float linv = 1.f / ls;
        const size_t obase = ((size_t)(b * 1024 + wq + 16 * t + fl)) * 512 + h * 64;
        #pragma unroll
        for (int jd = 0; jd < 4; jd++) {
            const ushort4 qr = *(const ushort4*)(Qb + (16 * t + fl) * 64 + 16 * jd + fq * 4);
            uint2 w2;
            w2.x = pack2(o[t][jd][0] * linv + bfu2f(qr.x), o[t][jd][1] * linv + bfu2f(qr.y));
            w2.y = pack2(o[t][jd][2] * linv + bfu2f(qr.z), o[t][jd][3] * linv + bfu2f(qr.w));
            *(uint2*)(&Oc[obase + 16 * jd + fq * 4]) = w2;
        }
    }
}

// ---------------------------------------------------------------------------
// LayerNorm over rows of 512 — wave/row, 8 consecutive elems/lane.
// ---------------------------------------------------------------------------
__global__ __launch_bounds__(256) void ln0(const bf16* __restrict__ X,
                                           const float* __restrict__ g,
                                           const float* __restrict__ be,
                                           bf16* __restrict__ Y)
{
    const int lane = threadIdx.x & 63;
    const int row = blockIdx.x * 4 + (threadIdx.x >> 6);
    const size_t base = (size_t)row * 512 + lane * 8;
    const bf16x8 xv = *(const bf16x8*)(X + base);
    float x[8];
    #pragma unroll
    for (int j = 0; j < 8; j++) x[j] = bfu2f((unsigned short)xv[j]);
    float s = 0.f, s2 = 0.f;
    #pragma unroll
    for (int j = 0; j < 8; j++) { s += x[j]; s2 += x[j] * x[j]; }
    s = wave_sum(s); s2 = wave_sum(s2);
    const float mean = s * (1.f / 512.f);
    const float var = s2 * (1.f / 512.f) - mean * mean;
    const float rs = rsqrtf(fmaxf(var, 0.f) + 1e-5f);
    const float4 gv0 = *(const float4*)(g + lane * 8);
    const float4 gv1 = *(const float4*)(g + lane * 8 + 4);
    const float4 bv0 = *(const float4*)(be + lane * 8);
    const float4 bv1 = *(const float4*)(be + lane * 8 + 4);
    uint4 ov;
    ov.x = pack2((x[0]-mean)*rs*gv0.x + bv0.x, (x[1]-mean)*rs*gv0.y + bv0.y);
    ov.y = pack2((x[2]-mean)*rs*gv0.z + bv0.z, (x[3]-mean)*rs*gv0.w + bv0.w);
    ov.z = pack2((x[4]-mean)*rs*gv1.x + bv1.x, (x[5]-mean)*rs*gv1.y + bv1.y);
    ov.w = pack2((x[6]-mean)*rs*gv1.z + bv1.z, (x[7]-mean)*rs*gv1.w + bv1.w);
    *(uint4*)(Y + base) = ov;
}

__global__ __launch_bounds__(256) void ln1(const bf16* __restrict__ X,
                                           const bf16* __restrict__ R,
                                           const float* __restrict__ g,
                                           const float* __restrict__ be,
                                           float* __restrict__ Y)
{
    const int lane = threadIdx.x & 63;
    const int row = blockIdx.x * 4 + (threadIdx.x >> 6);
    const size_t base = (size_t)row * 512 + lane * 8;
    const bf16x8 xv = *(const bf16x8*)(X + base);
    const bf16x8 rv = *(const bf16x8*)(R + base);
    float x[8];
    #pragma unroll
    for (int j = 0; j < 8; j++)
        x[j] = bfu2f((unsigned short)rv[j]) + fmaxf(bfu2f((unsigned short)xv[j]), 0.f);
    float s = 0.f, s2 = 0.f;
    #pragma unroll
    for (int j = 0; j < 8; j++) { s += x[j]; s2 += x[j] * x[j]; }
    s = wave_sum(s); s2 = wave_sum(s2);
    const float mean = s * (1.f / 512.f);
    const float var = s2 * (1.f / 512.f) - mean * mean;
    const float rs = rsqrtf(fmaxf(var, 0.f) + 1e-5f);
    const float4 gv0 = *(const float4*)(g + lane * 8);
    const float4 gv1 = *(const float4*)(g + lane * 8 + 4);
    const float4 bv0 = *(const float4*)(be + lane * 8);
    const float4 bv1 = *(const float4*)(be + lane * 8 + 4);
    float4 y0, y1;
    y0.x = (x[0]-mean)*rs*gv0.x + bv0.x; y0.y = (x[1]-mean)*rs*gv0.y + bv0.y;
    y0.z = (x[2]-mean)*rs*gv0.z + bv0.z; y0.w = (x[3]-mean)*rs*gv0.w + bv0.w;
    y1.x = (x[4]-mean)*rs*gv1.x + bv1.x; y1.y = (x[5]-mean)*rs*gv1.y + bv1.y;
    y1.z = (x[6]-mean)*rs*gv1.z + bv1.z; y1.w = (x[7]-mean)*rs*gv1.w + bv1.w;
    *(float4*)(Y + base)     = y0;
    *(float4*)(Y + base + 4) = y1;
}

// ---------------------------------------------------------------------------
extern "C" void kernel_launch(void* const* d_in, const int* in_sizes, int n_in,
                              void* d_out, int out_size, void* d_ws, size_t ws_size,
                              hipStream_t stream)
{
    const float* Q   = (const float*)d_in[0];
    const float* K   = (const float*)d_in[1];
    const float* Wq  = (const float*)d_in[2];
    const float* bq  = (const float*)d_in[3];
    const float* Wk  = (const float*)d_in[4];
    const float* bk  = (const float*)d_in[5];
    const float* Wv  = (const float*)d_in[6];
    const float* bv  = (const float*)d_in[7];
    const float* Wo  = (const float*)d_in[8];
    const float* bo  = (const float*)d_in[9];
    const float* g0  = (const float*)d_in[10];
    const float* be0 = (const float*)d_in[11];
    const float* g1  = (const float*)d_in[12];
    const float* be1 = (const float*)d_in[13];
    float* out = (float*)d_out;

    const size_t NQK = (size_t)8 * 1024 * 512;  // 4M
    const size_t NW  = (size_t)512 * 512;       // 256K
    bf16* ws   = (bf16*)d_ws;
    bf16* cQ   = ws;
    bf16* cK   = cQ + NQK;
    bf16* cWq  = cK + NQK;
    bf16* cWk  = cWq + NW;
    bf16* cWv  = cWk + NW;
    bf16* cWo  = cWv + NW;
    bf16* pQh  = cWo + NW;           // [b,h,n,d]
    bf16* pKh  = pQh + NQK;          // [b,h,m,d]
    bf16* pVhT = pKh + NQK;          // [b,h,d,m]
    bf16* pOc  = (bf16*)d_out;       // attn output staged in d_out
    bf16* pO1  = pKh;                // Kh dead after attn
    bf16* pTmp = pQh;                // Qh dead after attn

    castall<<<2304, 256, 0, stream>>>(Q, K, Wq, Wk, Wv, Wo, cQ, cK, cWq, cWk, cWv, cWo);
    gemm_qkv<<<dim3(64, 12), 256, 0, stream>>>(cQ, cK, cWq, cWk, cWv, bq, bk, bv, pQh, pKh, pVhT);
    attn_mfma<<<512, 256, 0, stream>>>(pQh, pKh, pVhT, pOc);
    ln0<<<2048, 256, 0, stream>>>(pOc, g0, be0, pO1);
    gemm_o<<<dim3(128, 4), 256, 0, stream>>>(pO1, cWo, bo, pTmp);
    ln1<<<2048, 256, 0, stream>>>(pTmp, pO1, g1, be1, out);
}